// Round 3
// baseline (591.463 us; speedup 1.0000x reference)
//
#include <hip/hip_runtime.h>
#include <math.h>

// B=4096, S=200, D=64, H=36
#define BB 4096
#define SS 200
#define DD 64
#define HH 36
#define NP 48           // H padded to 3 n-tiles of 16
#define LDH 68          // LDS row stride (bf16 units): 64 + 4 pad
#define NROWSF (4096.0f * 200.0f)

typedef short bf16x8 __attribute__((ext_vector_type(8)));
typedef float f32x4 __attribute__((ext_vector_type(4)));

__device__ __forceinline__ unsigned short f2bf(float f) {
    union { float f; unsigned u; } v; v.f = f;
    unsigned r = v.u + 0x7FFFu + ((v.u >> 16) & 1u);   // RNE
    return (unsigned short)(r >> 16);
}

// ---------------------------------------------------------------------------
// Prologue: deep-pipelined hist staging (7 float4 loads in flight per thread)
// + folded WbT/base build. half0: tiles 0-6 (rows 0-111); half1: tiles 7-12
// (rows 112-199 + 8 zero pad rows).
// ---------------------------------------------------------------------------
__device__ __forceinline__ void prologue(int b, int half, int t,
                                         const float* __restrict__ hist,
                                         const float* __restrict__ cand,
                                         const float* __restrict__ W1,
                                         const float* __restrict__ b1,
                                         unsigned short* shH, unsigned short* shWbT,
                                         float* shC, float* shBase,
                                         float (*shBaseP)[NP]) {
    const int rowLo = half ? 112 : 0;
    const int nflt4 = half ? (88 * 16) : (112 * 16);
    // ---- phase 0: issue ALL global hist loads (stay in VGPRs), shC, pads ----
    float4 v[7];
    const float4* src = (const float4*)(hist + ((size_t)b * SS + rowLo) * DD);
#pragma unroll
    for (int u = 0; u < 7; ++u) {
        int i = t + u * 256;
        if (i < nflt4) v[u] = src[i];
    }
    if (t < DD) shC[t] = cand[b * DD + t];
    if (half) {  // zero pad rows (local 88..95) for the ragged last tile
        for (int i = t; i < 8 * DD; i += 256)
            shH[(88 + (i >> 6)) * LDH + (i & 63)] = 0;
    }
    __syncthreads();
    // ---- phase 1: drain loads -> bf16 LDS; build WbT + base partials ----
#pragma unroll
    for (int u = 0; u < 7; ++u) {
        int i = t + u * 256;
        if (i < nflt4) {
            int s = i >> 4, c = i & 15;
            ushort4 o;
            o.x = f2bf(v[u].x); o.y = f2bf(v[u].y); o.z = f2bf(v[u].z); o.w = f2bf(v[u].w);
            *(ushort4*)&shH[s * LDH + c * 4] = o;
        }
    }
    // WbT[n][k] = W1b - W1c + c_k*W1d  (bf16, transposed; n>=36 zero)
    for (int e = t; e < NP * DD; e += 256) {
        int k = e / NP, n = e - k * NP;
        float val = 0.f;
        if (n < HH)
            val = W1[(DD + k) * HH + n] - W1[(2 * DD + k) * HH + n] +
                  shC[k] * W1[(3 * DD + k) * HH + n];
        shWbT[n * LDH + k] = f2bf(val);
    }
    if (t < 4 * NP) {  // base[j] partials: 4 groups of 16 k's
        int g = t / NP, j = t - g * NP;
        float p = 0.f;
        if (j < HH) {
#pragma unroll 4
            for (int k = 16 * g; k < 16 * g + 16; ++k)
                p += shC[k] * (W1[k * HH + j] + W1[(2 * DD + k) * HH + j]);
        }
        shBaseP[g][j] = p;
    }
    __syncthreads();
    if (t < NP) {
        float val = (t < HH) ? b1[t] : 0.f;
        shBase[t] = val + shBaseP[0][t] + shBaseP[1][t] + shBaseP[2][t] + shBaseP[3][t];
    }
    __syncthreads();
}

__device__ __forceinline__ void load_bfrags(const unsigned short* shWbT, int lane,
                                            bf16x8 (&bfr)[3][2]) {
    int col = lane & 15, q = lane >> 4;
#pragma unroll
    for (int nt = 0; nt < 3; ++nt)
#pragma unroll
        for (int kt = 0; kt < 2; ++kt)
            bfr[nt][kt] = *(const bf16x8*)&shWbT[(nt * 16 + col) * LDH + kt * 32 + q * 8];
}

__device__ __forceinline__ void gemm_tile(const unsigned short* shH,
                                          const bf16x8 (&bfr)[3][2], int mt, int lane,
                                          f32x4 (&d)[3]) {
    int m = mt * 16 + (lane & 15), q = lane >> 4;
    d[0] = f32x4{0.f, 0.f, 0.f, 0.f};
    d[1] = f32x4{0.f, 0.f, 0.f, 0.f};
    d[2] = f32x4{0.f, 0.f, 0.f, 0.f};
#pragma unroll
    for (int kt = 0; kt < 2; ++kt) {
        bf16x8 a = *(const bf16x8*)&shH[m * LDH + kt * 32 + q * 8];
#pragma unroll
        for (int nt = 0; nt < 3; ++nt)
            d[nt] = __builtin_amdgcn_mfma_f32_16x16x32_bf16(a, bfr[nt][kt], d[nt], 0, 0, 0);
    }
}

// ---------------------------------------------------------------------------
// Pass 1: column sums of h and h^2 (BN batch statistics)
// ---------------------------------------------------------------------------
__global__ __launch_bounds__(256, 6) void k_pass1(const float* __restrict__ hist,
                                                  const float* __restrict__ cand,
                                                  const float* __restrict__ W1,
                                                  const float* __restrict__ b1,
                                                  float* __restrict__ gsum,
                                                  float* __restrict__ gsum2) {
    __shared__ unsigned short shH[112 * LDH];
    __shared__ unsigned short shWbT[NP * LDH];
    __shared__ float shC[DD], shBase[NP];
    __shared__ float shBaseP[4][NP];
    __shared__ float shP1[4][NP], shP2[4][NP];
    int bx = blockIdx.x, b = bx >> 1, half = bx & 1;
    int t = threadIdx.x, wave = t >> 6, lane = t & 63;
    int col = lane & 15, q = lane >> 4;

    prologue(b, half, t, hist, cand, W1, b1, shH, shWbT, shC, shBase, shBaseP);

    bf16x8 bfr[3][2];
    load_bfrags(shWbT, lane, bfr);
    float basev[3];
#pragma unroll
    for (int nt = 0; nt < 3; ++nt) basev[nt] = shBase[nt * 16 + col];

    const int T0 = half ? 7 : 0, NTl = half ? 6 : 7;
    float cs1[3] = {0.f, 0.f, 0.f}, cs2[3] = {0.f, 0.f, 0.f};
    for (int mt = wave; mt < NTl; mt += 4) {
        f32x4 d[3];
        gemm_tile(shH, bfr, mt, lane, d);
        int grow0 = (T0 + mt) * 16 + q * 4;
#pragma unroll
        for (int nt = 0; nt < 3; ++nt)
#pragma unroll
            for (int r = 0; r < 4; ++r) {
                if (grow0 + r < SS) {
                    float vv = d[nt][r] + basev[nt];
                    cs1[nt] += vv;
                    cs2[nt] += vv * vv;
                }
            }
    }
#pragma unroll
    for (int nt = 0; nt < 3; ++nt) {
        cs1[nt] += __shfl_xor(cs1[nt], 16);
        cs1[nt] += __shfl_xor(cs1[nt], 32);
        cs2[nt] += __shfl_xor(cs2[nt], 16);
        cs2[nt] += __shfl_xor(cs2[nt], 32);
    }
    if (lane < 16) {
#pragma unroll
        for (int nt = 0; nt < 3; ++nt) {
            shP1[wave][nt * 16 + lane] = cs1[nt];
            shP2[wave][nt * 16 + lane] = cs2[nt];
        }
    }
    __syncthreads();
    if (t < HH) {
        atomicAdd(gsum + t, shP1[0][t] + shP1[1][t] + shP1[2][t] + shP1[3][t]);
        atomicAdd(gsum2 + t, shP2[0][t] + shP2[1][t] + shP2[2][t] + shP2[3][t]);
    }
}

// ---------------------------------------------------------------------------
__global__ void k_stats(const float* __restrict__ gsum, const float* __restrict__ gsum2,
                        const float* __restrict__ gamma, const float* __restrict__ beta,
                        float* __restrict__ A, float* __restrict__ Bc) {
    int t = threadIdx.x;
    if (t < NP) {
        if (t < HH) {
            float mu = gsum[t] * (1.0f / NROWSF);
            float var = gsum2[t] * (1.0f / NROWSF) - mu * mu;
            float rs = rsqrtf(var + 1e-5f);
            float a = rs * gamma[t];
            A[t] = a;
            Bc[t] = beta[t] - mu * a;
        } else {
            A[t] = 0.f;
            Bc[t] = 0.f;
        }
    }
}

// ---------------------------------------------------------------------------
// Pass 2: h -> BN affine -> Dice -> output linear -> weighted-sum pooling
// ---------------------------------------------------------------------------
__global__ __launch_bounds__(256, 6) void k_pass2(const float* __restrict__ hist,
                                                  const float* __restrict__ cand,
                                                  const float* __restrict__ W1,
                                                  const float* __restrict__ b1,
                                                  const float* __restrict__ Acoef,
                                                  const float* __restrict__ Bcoef,
                                                  const float* __restrict__ alpha,
                                                  const float* __restrict__ W2,
                                                  const float* __restrict__ b2,
                                                  float* __restrict__ out) {
    __shared__ unsigned short shH[112 * LDH];
    __shared__ unsigned short shWbT[NP * LDH];
    __shared__ float shC[DD], shBase[NP];
    __shared__ float shBaseP[4][NP];
    __shared__ float shW[112];
    __shared__ float shPool[4][DD];
    int bx = blockIdx.x, b = bx >> 1, half = bx & 1;
    int t = threadIdx.x, wave = t >> 6, lane = t & 63;
    int col = lane & 15, q = lane >> 4;

    prologue(b, half, t, hist, cand, W1, b1, shH, shWbT, shC, shBase, shBaseP);

    bf16x8 bfr[3][2];
    load_bfrags(shWbT, lane, bfr);
    float basev[3], Ar[3], Br[3], W2r[3];
#pragma unroll
    for (int nt = 0; nt < 3; ++nt) {
        int c = nt * 16 + col;
        basev[nt] = shBase[c];
        Ar[nt] = Acoef[c];
        Br[nt] = Bcoef[c];
        W2r[nt] = (c < HH) ? W2[c] : 0.f;
    }
    float alv = alpha[0], b2v = b2[0];

    const int T0 = half ? 7 : 0, NTl = half ? 6 : 7;
    for (int mt = wave; mt < NTl; mt += 4) {
        f32x4 d[3];
        gemm_tile(shH, bfr, mt, lane, d);
        float hp[3][4];
#pragma unroll
        for (int nt = 0; nt < 3; ++nt)
#pragma unroll
            for (int r = 0; r < 4; ++r)
                hp[nt][r] = fmaf(d[nt][r] + basev[nt], Ar[nt], Br[nt]);
        float s1[4], s2[4], wsum[4];
#pragma unroll
        for (int r = 0; r < 4; ++r) {
            s1[r] = hp[0][r] + hp[1][r] + hp[2][r];
            s2[r] = hp[0][r] * hp[0][r] + hp[1][r] * hp[1][r] + hp[2][r] * hp[2][r];
            s1[r] += __shfl_xor(s1[r], 1);
            s1[r] += __shfl_xor(s1[r], 2);
            s1[r] += __shfl_xor(s1[r], 4);
            s1[r] += __shfl_xor(s1[r], 8);
            s2[r] += __shfl_xor(s2[r], 1);
            s2[r] += __shfl_xor(s2[r], 2);
            s2[r] += __shfl_xor(s2[r], 4);
            s2[r] += __shfl_xor(s2[r], 8);
        }
#pragma unroll
        for (int r = 0; r < 4; ++r) {
            float avg = s1[r] * (1.0f / (float)HH);
            float var = s2[r] * (1.0f / (float)HH) - avg * avg;
            float inv = rsqrtf(var + 1e-3f);
            float wv = 0.f;
#pragma unroll
            for (int nt = 0; nt < 3; ++nt) {
                float z = (hp[nt][r] - avg) * inv;
                float ps = 1.0f / (1.0f + __expf(-z));
                float f = ps + (1.0f - ps) * alv;
                wv = fmaf(hp[nt][r] * f, W2r[nt], wv);
            }
            wsum[r] = wv;
            wsum[r] += __shfl_xor(wsum[r], 1);
            wsum[r] += __shfl_xor(wsum[r], 2);
            wsum[r] += __shfl_xor(wsum[r], 4);
            wsum[r] += __shfl_xor(wsum[r], 8);
        }
        int grow0 = (T0 + mt) * 16 + q * 4;
        if (col == 0 && grow0 + 3 < SS) {
            float4 o = {wsum[0] + b2v, wsum[1] + b2v, wsum[2] + b2v, wsum[3] + b2v};
            *(float4*)&shW[mt * 16 + q * 4] = o;
        }
    }
    __syncthreads();
    // pooling over this half's rows: out[b][d] += sum_s w[s]*hist[s][d] (fp32)
    {
        const int rowLo = T0 * 16, nR = half ? 88 : 112;
        const float* hb = hist + (size_t)b * SS * DD;
        float p = 0.f;
        for (int s = wave; s < nR; s += 4)
            p = fmaf(shW[s], hb[(size_t)(rowLo + s) * DD + lane], p);
        shPool[wave][lane] = p;
    }
    __syncthreads();
    if (t < DD)
        atomicAdd(out + b * DD + t,
                  shPool[0][t] + shPool[1][t] + shPool[2][t] + shPool[3][t]);
}

// ---------------------------------------------------------------------------
extern "C" void kernel_launch(void* const* d_in, const int* in_sizes, int n_in,
                              void* d_out, int out_size, void* d_ws, size_t ws_size,
                              hipStream_t stream) {
    const float* hist = (const float*)d_in[0];
    const float* cand = (const float*)d_in[1];
    const float* W1 = (const float*)d_in[2];
    const float* b1 = (const float*)d_in[3];
    const float* gamma = (const float*)d_in[4];
    const float* beta = (const float*)d_in[5];
    const float* alpha = (const float*)d_in[6];
    const float* W2 = (const float*)d_in[7];
    const float* b2 = (const float*)d_in[8];
    float* out = (float*)d_out;
    float* ws = (float*)d_ws;

    float* gsum = ws;
    float* gsum2 = ws + NP;
    float* A = ws + 2 * NP;
    float* Bc = ws + 3 * NP;

    hipMemsetAsync(gsum, 0, 2 * NP * sizeof(float), stream);
    hipMemsetAsync(out, 0, (size_t)out_size * sizeof(float), stream);
    k_pass1<<<2 * BB, 256, 0, stream>>>(hist, cand, W1, b1, gsum, gsum2);
    k_stats<<<1, 64, 0, stream>>>(gsum, gsum2, gamma, beta, A, Bc);
    k_pass2<<<2 * BB, 256, 0, stream>>>(hist, cand, W1, b1, A, Bc, alpha, W2, b2, out);
}

// Round 4
// 525.954 us; speedup vs baseline: 1.1246x; 1.1246x over previous
//
#include <hip/hip_runtime.h>
#include <math.h>

// B=4096, S=200, D=64, H=36
#define BB 4096
#define SS 200
#define DD 64
#define HH 36
#define NP 48            // H padded to 3 n-tiles of 16
#define LDH 68           // LDS row stride (bf16 units): 64 + 4 pad
#define NROWSF (4096.0f * 200.0f)
#define NPB (2 * BB)     // 8192 blocks: (b, half)
#define PSTRIDE 80       // per-block partial-stat row stride (dwords)

typedef short bf16x8 __attribute__((ext_vector_type(8)));
typedef float f32x4 __attribute__((ext_vector_type(4)));

__device__ __forceinline__ unsigned short f2bf(float f) {
    union { float f; unsigned u; } v; v.f = f;
    unsigned r = v.u + 0x7FFFu + ((v.u >> 16) & 1u);   // RNE
    return (unsigned short)(r >> 16);
}

// ---------------------------------------------------------------------------
// Prologue: stage half of hist (fp32->bf16, padded) + folded WbT/base build.
// half0: tiles 0-6 (rows 0-111); half1: tiles 7-12 (rows 112-199 + 8 pad rows)
// ---------------------------------------------------------------------------
__device__ __forceinline__ void prologue(int b, int half, int t,
                                         const float* __restrict__ hist,
                                         const float* __restrict__ cand,
                                         const float* __restrict__ W1,
                                         const float* __restrict__ b1,
                                         unsigned short* shH, unsigned short* shWbT,
                                         float* shC, float* shBase,
                                         float (*shBaseP)[NP]) {
    const int rowLo = half ? 112 : 0;
    const int nflt4 = half ? (88 * 16) : (112 * 16);
    if (t < DD) shC[t] = cand[b * DD + t];
    if (half) {  // zero pad rows (local 88..95) for the ragged last tile
        for (int i = t; i < 8 * DD; i += 256)
            shH[(88 + (i >> 6)) * LDH + (i & 63)] = 0;
    }
    __syncthreads();
    // hist tile: coalesced float4 global reads -> bf16x4 LDS writes
    const float4* src = (const float4*)(hist + ((size_t)b * SS + rowLo) * DD);
    for (int i = t; i < nflt4; i += 256) {
        float4 v = src[i];
        int s = i >> 4, c = i & 15;
        ushort4 o;
        o.x = f2bf(v.x); o.y = f2bf(v.y); o.z = f2bf(v.z); o.w = f2bf(v.w);
        *(ushort4*)&shH[s * LDH + c * 4] = o;
    }
    // WbT[n][k] = W1b - W1c + c_k*W1d  (bf16, transposed; n>=36 zero)
    for (int e = t; e < NP * DD; e += 256) {
        int k = e / NP, n = e - k * NP;
        float val = 0.f;
        if (n < HH)
            val = W1[(DD + k) * HH + n] - W1[(2 * DD + k) * HH + n] +
                  shC[k] * W1[(3 * DD + k) * HH + n];
        shWbT[n * LDH + k] = f2bf(val);
    }
    if (t < 4 * NP) {  // base[j] partials: 4 groups of 16 k's
        int g = t / NP, j = t - g * NP;
        float p = 0.f;
        if (j < HH) {
#pragma unroll 4
            for (int k = 16 * g; k < 16 * g + 16; ++k)
                p += shC[k] * (W1[k * HH + j] + W1[(2 * DD + k) * HH + j]);
        }
        shBaseP[g][j] = p;
    }
    __syncthreads();
    if (t < NP) {
        float val = (t < HH) ? b1[t] : 0.f;
        shBase[t] = val + shBaseP[0][t] + shBaseP[1][t] + shBaseP[2][t] + shBaseP[3][t];
    }
    __syncthreads();
}

__device__ __forceinline__ void load_bfrags(const unsigned short* shWbT, int lane,
                                            bf16x8 (&bfr)[3][2]) {
    int col = lane & 15, q = lane >> 4;
#pragma unroll
    for (int nt = 0; nt < 3; ++nt)
#pragma unroll
        for (int kt = 0; kt < 2; ++kt)
            bfr[nt][kt] = *(const bf16x8*)&shWbT[(nt * 16 + col) * LDH + kt * 32 + q * 8];
}

__device__ __forceinline__ void gemm_tile(const unsigned short* shH,
                                          const bf16x8 (&bfr)[3][2], int mt, int lane,
                                          f32x4 (&d)[3]) {
    int m = mt * 16 + (lane & 15), q = lane >> 4;
    d[0] = f32x4{0.f, 0.f, 0.f, 0.f};
    d[1] = f32x4{0.f, 0.f, 0.f, 0.f};
    d[2] = f32x4{0.f, 0.f, 0.f, 0.f};
#pragma unroll
    for (int kt = 0; kt < 2; ++kt) {
        bf16x8 a = *(const bf16x8*)&shH[m * LDH + kt * 32 + q * 8];
#pragma unroll
        for (int nt = 0; nt < 3; ++nt)
            d[nt] = __builtin_amdgcn_mfma_f32_16x16x32_bf16(a, bfr[nt][kt], d[nt], 0, 0, 0);
    }
}

// ---------------------------------------------------------------------------
// Pass 1: column sums of h and h^2 (BN batch statistics)
// RED=true: write per-block partials to pstat[bx*PSTRIDE+{0..71}] (no atomics)
// RED=false: atomicAdd fallback (tiny ws)
// ---------------------------------------------------------------------------
template <bool RED>
__global__ __launch_bounds__(256, 6) void k_pass1(const float* __restrict__ hist,
                                                  const float* __restrict__ cand,
                                                  const float* __restrict__ W1,
                                                  const float* __restrict__ b1,
                                                  float* __restrict__ pstat,
                                                  float* __restrict__ gsum,
                                                  float* __restrict__ gsum2) {
    __shared__ unsigned short shH[112 * LDH];
    __shared__ unsigned short shWbT[NP * LDH];
    __shared__ float shC[DD], shBase[NP];
    __shared__ float shBaseP[4][NP];
    __shared__ float shP1[4][NP], shP2[4][NP];
    int bx = blockIdx.x, b = bx >> 1, half = bx & 1;
    int t = threadIdx.x, wave = t >> 6, lane = t & 63;
    int col = lane & 15, q = lane >> 4;

    prologue(b, half, t, hist, cand, W1, b1, shH, shWbT, shC, shBase, shBaseP);

    bf16x8 bfr[3][2];
    load_bfrags(shWbT, lane, bfr);
    float basev[3];
#pragma unroll
    for (int nt = 0; nt < 3; ++nt) basev[nt] = shBase[nt * 16 + col];

    const int T0 = half ? 7 : 0, NTl = half ? 6 : 7;
    float cs1[3] = {0.f, 0.f, 0.f}, cs2[3] = {0.f, 0.f, 0.f};
    for (int mt = wave; mt < NTl; mt += 4) {
        f32x4 d[3];
        gemm_tile(shH, bfr, mt, lane, d);
        int grow0 = (T0 + mt) * 16 + q * 4;
#pragma unroll
        for (int nt = 0; nt < 3; ++nt)
#pragma unroll
            for (int r = 0; r < 4; ++r) {
                if (grow0 + r < SS) {
                    float vv = d[nt][r] + basev[nt];
                    cs1[nt] += vv;
                    cs2[nt] += vv * vv;
                }
            }
    }
#pragma unroll
    for (int nt = 0; nt < 3; ++nt) {
        cs1[nt] += __shfl_xor(cs1[nt], 16);
        cs1[nt] += __shfl_xor(cs1[nt], 32);
        cs2[nt] += __shfl_xor(cs2[nt], 16);
        cs2[nt] += __shfl_xor(cs2[nt], 32);
    }
    if (lane < 16) {
#pragma unroll
        for (int nt = 0; nt < 3; ++nt) {
            shP1[wave][nt * 16 + lane] = cs1[nt];
            shP2[wave][nt * 16 + lane] = cs2[nt];
        }
    }
    __syncthreads();
    if (RED) {
        // coalesced non-atomic partial write: 72 dwords per block
        if (t < HH)
            pstat[(size_t)bx * PSTRIDE + t] =
                shP1[0][t] + shP1[1][t] + shP1[2][t] + shP1[3][t];
        else if (t < 2 * HH) {
            int f = t - HH;
            pstat[(size_t)bx * PSTRIDE + t] =
                shP2[0][f] + shP2[1][f] + shP2[2][f] + shP2[3][f];
        }
    } else {
        if (t < HH) {
            atomicAdd(gsum + t, shP1[0][t] + shP1[1][t] + shP1[2][t] + shP1[3][t]);
            atomicAdd(gsum2 + t, shP2[0][t] + shP2[1][t] + shP2[2][t] + shP2[3][t]);
        }
    }
}

// ---------------------------------------------------------------------------
// Stats (RED path): 48 blocks, block f reduces feature-f partials over 8192
// rows and emits folded BN affine A/Bc. Deterministic (fixed reduction tree).
// ---------------------------------------------------------------------------
__global__ __launch_bounds__(256) void k_stats_red(const float* __restrict__ pstat,
                                                   const float* __restrict__ gamma,
                                                   const float* __restrict__ beta,
                                                   float* __restrict__ A,
                                                   float* __restrict__ Bc) {
    int f = blockIdx.x, t = threadIdx.x;
    if (f >= HH) {
        if (t == 0) { A[f] = 0.f; Bc[f] = 0.f; }
        return;
    }
    float s1 = 0.f, s2 = 0.f;
    for (int r = t; r < NPB; r += 256) {
        s1 += pstat[(size_t)r * PSTRIDE + f];
        s2 += pstat[(size_t)r * PSTRIDE + HH + f];
    }
#pragma unroll
    for (int off = 1; off < 64; off <<= 1) {
        s1 += __shfl_xor(s1, off);
        s2 += __shfl_xor(s2, off);
    }
    __shared__ float a1[4], a2[4];
    if ((t & 63) == 0) { a1[t >> 6] = s1; a2[t >> 6] = s2; }
    __syncthreads();
    if (t == 0) {
        s1 = a1[0] + a1[1] + a1[2] + a1[3];
        s2 = a2[0] + a2[1] + a2[2] + a2[3];
        float mu = s1 * (1.0f / NROWSF);
        float var = s2 * (1.0f / NROWSF) - mu * mu;
        float a = rsqrtf(var + 1e-5f) * gamma[f];
        A[f] = a;
        Bc[f] = beta[f] - mu * a;
    }
}

// Atomic-fallback stats
__global__ void k_stats(const float* __restrict__ gsum, const float* __restrict__ gsum2,
                        const float* __restrict__ gamma, const float* __restrict__ beta,
                        float* __restrict__ A, float* __restrict__ Bc) {
    int t = threadIdx.x;
    if (t < NP) {
        if (t < HH) {
            float mu = gsum[t] * (1.0f / NROWSF);
            float var = gsum2[t] * (1.0f / NROWSF) - mu * mu;
            float a = rsqrtf(var + 1e-5f) * gamma[t];
            A[t] = a;
            Bc[t] = beta[t] - mu * a;
        } else {
            A[t] = 0.f;
            Bc[t] = 0.f;
        }
    }
}

// ---------------------------------------------------------------------------
// Pass 2: h -> BN affine -> Dice -> output linear -> weighted-sum pooling
// ---------------------------------------------------------------------------
__global__ __launch_bounds__(256, 6) void k_pass2(const float* __restrict__ hist,
                                                  const float* __restrict__ cand,
                                                  const float* __restrict__ W1,
                                                  const float* __restrict__ b1,
                                                  const float* __restrict__ Acoef,
                                                  const float* __restrict__ Bcoef,
                                                  const float* __restrict__ alpha,
                                                  const float* __restrict__ W2,
                                                  const float* __restrict__ b2,
                                                  float* __restrict__ out) {
    __shared__ unsigned short shH[112 * LDH];
    __shared__ unsigned short shWbT[NP * LDH];
    __shared__ float shC[DD], shBase[NP];
    __shared__ float shBaseP[4][NP];
    __shared__ float shW[112];
    __shared__ float shPool[4][DD];
    int bx = blockIdx.x, b = bx >> 1, half = bx & 1;
    int t = threadIdx.x, wave = t >> 6, lane = t & 63;
    int col = lane & 15, q = lane >> 4;

    prologue(b, half, t, hist, cand, W1, b1, shH, shWbT, shC, shBase, shBaseP);

    bf16x8 bfr[3][2];
    load_bfrags(shWbT, lane, bfr);
    float basev[3], Ar[3], Br[3], W2r[3];
#pragma unroll
    for (int nt = 0; nt < 3; ++nt) {
        int c = nt * 16 + col;
        basev[nt] = shBase[c];
        Ar[nt] = Acoef[c];
        Br[nt] = Bcoef[c];
        W2r[nt] = (c < HH) ? W2[c] : 0.f;
    }
    float alv = alpha[0], b2v = b2[0];

    const int T0 = half ? 7 : 0, NTl = half ? 6 : 7;
    for (int mt = wave; mt < NTl; mt += 4) {
        f32x4 d[3];
        gemm_tile(shH, bfr, mt, lane, d);
        float hp[3][4];
#pragma unroll
        for (int nt = 0; nt < 3; ++nt)
#pragma unroll
            for (int r = 0; r < 4; ++r)
                hp[nt][r] = fmaf(d[nt][r] + basev[nt], Ar[nt], Br[nt]);
        float s1[4], s2[4], wsum[4];
#pragma unroll
        for (int r = 0; r < 4; ++r) {
            s1[r] = hp[0][r] + hp[1][r] + hp[2][r];
            s2[r] = hp[0][r] * hp[0][r] + hp[1][r] * hp[1][r] + hp[2][r] * hp[2][r];
            s1[r] += __shfl_xor(s1[r], 1);
            s1[r] += __shfl_xor(s1[r], 2);
            s1[r] += __shfl_xor(s1[r], 4);
            s1[r] += __shfl_xor(s1[r], 8);
            s2[r] += __shfl_xor(s2[r], 1);
            s2[r] += __shfl_xor(s2[r], 2);
            s2[r] += __shfl_xor(s2[r], 4);
            s2[r] += __shfl_xor(s2[r], 8);
        }
#pragma unroll
        for (int r = 0; r < 4; ++r) {
            float avg = s1[r] * (1.0f / (float)HH);
            float var = s2[r] * (1.0f / (float)HH) - avg * avg;
            float inv = rsqrtf(var + 1e-3f);
            float wv = 0.f;
#pragma unroll
            for (int nt = 0; nt < 3; ++nt) {
                float z = (hp[nt][r] - avg) * inv;
                float ps = 1.0f / (1.0f + __expf(-z));
                float f = ps + (1.0f - ps) * alv;
                wv = fmaf(hp[nt][r] * f, W2r[nt], wv);
            }
            wsum[r] = wv;
            wsum[r] += __shfl_xor(wsum[r], 1);
            wsum[r] += __shfl_xor(wsum[r], 2);
            wsum[r] += __shfl_xor(wsum[r], 4);
            wsum[r] += __shfl_xor(wsum[r], 8);
        }
        int grow0 = (T0 + mt) * 16 + q * 4;
        if (col == 0 && grow0 + 3 < SS) {
            float4 o = {wsum[0] + b2v, wsum[1] + b2v, wsum[2] + b2v, wsum[3] + b2v};
            *(float4*)&shW[mt * 16 + q * 4] = o;
        }
    }
    __syncthreads();
    // pooling over this half's rows: out[b][d] += sum_s w[s]*hist[s][d] (fp32)
    {
        const int rowLo = T0 * 16, nR = half ? 88 : 112;
        const float* hb = hist + (size_t)b * SS * DD;
        float p = 0.f;
        for (int s = wave; s < nR; s += 4)
            p = fmaf(shW[s], hb[(size_t)(rowLo + s) * DD + lane], p);
        shPool[wave][lane] = p;
    }
    __syncthreads();
    if (t < DD)
        atomicAdd(out + b * DD + t,
                  shPool[0][t] + shPool[1][t] + shPool[2][t] + shPool[3][t]);
}

// ---------------------------------------------------------------------------
extern "C" void kernel_launch(void* const* d_in, const int* in_sizes, int n_in,
                              void* d_out, int out_size, void* d_ws, size_t ws_size,
                              hipStream_t stream) {
    const float* hist = (const float*)d_in[0];
    const float* cand = (const float*)d_in[1];
    const float* W1 = (const float*)d_in[2];
    const float* b1 = (const float*)d_in[3];
    const float* gamma = (const float*)d_in[4];
    const float* beta = (const float*)d_in[5];
    const float* alpha = (const float*)d_in[6];
    const float* W2 = (const float*)d_in[7];
    const float* b2 = (const float*)d_in[8];
    float* out = (float*)d_out;
    float* ws = (float*)d_ws;

    const size_t pstatF = (size_t)NPB * PSTRIDE;                 // 655360 floats
    bool red = ws_size >= (pstatF + 2 * NP) * sizeof(float);     // ~2.63 MB

    hipMemsetAsync(out, 0, (size_t)out_size * sizeof(float), stream);
    if (red) {
        float* pstat = ws;
        float* A = ws + pstatF;
        float* Bc = A + NP;
        k_pass1<true><<<NPB, 256, 0, stream>>>(hist, cand, W1, b1, pstat, nullptr, nullptr);
        k_stats_red<<<NP, 256, 0, stream>>>(pstat, gamma, beta, A, Bc);
        k_pass2<<<NPB, 256, 0, stream>>>(hist, cand, W1, b1, A, Bc, alpha, W2, b2, out);
    } else {
        float* gsum = ws;
        float* gsum2 = ws + NP;
        float* A = ws + 2 * NP;
        float* Bc = ws + 3 * NP;
        hipMemsetAsync(gsum, 0, 2 * NP * sizeof(float), stream);
        k_pass1<false><<<NPB, 256, 0, stream>>>(hist, cand, W1, b1, nullptr, gsum, gsum2);
        k_stats<<<1, 64, 0, stream>>>(gsum, gsum2, gamma, beta, A, Bc);
        k_pass2<<<NPB, 256, 0, stream>>>(hist, cand, W1, b1, A, Bc, alpha, W2, b2, out);
    }
}

// Round 5
// 430.215 us; speedup vs baseline: 1.3748x; 1.2225x over previous
//
#include <hip/hip_runtime.h>
#include <hip/hip_bf16.h>
#include <math.h>

// B=4096, S=200, D=64, H=36
#define BB 4096
#define SS 200
#define DD 64
#define HH 36
#define NP 48            // H padded to 3 n-tiles of 16
#define LDH 72           // LDS row stride (bf16): 144 B rows -> 16B-aligned b128
#define NROWSF (4096.0f * 200.0f)
#define NPB (2 * BB)     // 8192 blocks: (b, half)
#define PSTRIDE 80       // per-block partial-stat row stride (dwords)

typedef short bf16x8 __attribute__((ext_vector_type(8)));
typedef float f32x4 __attribute__((ext_vector_type(4)));

__device__ __forceinline__ unsigned short f2bf(float f) {
    union { float f; unsigned u; } v; v.f = f;
    unsigned r = v.u + 0x7FFFu + ((v.u >> 16) & 1u);   // RNE
    return (unsigned short)(r >> 16);
}
__device__ __forceinline__ unsigned f2bf2(float a, float b) {
    union { __hip_bfloat162 h; unsigned u; } v;
    v.h = __float22bfloat162_rn(float2{a, b});         // packed cvt on gfx950
    return v.u;
}
__device__ __forceinline__ float bf2f(unsigned short h) {
    union { unsigned u; float f; } v; v.u = (unsigned)h << 16;
    return v.f;
}

// ---------------------------------------------------------------------------
// k_wb: per-b folded weights/bias, computed ONCE (was rebuilt in every block
// of both passes). WbG[b][n][k] bf16 (n<36 real, else 0); baseG[b][0..47].
//   Wb[k][n] = W1b[k][n] - W1c[k][n] + c[k]*W1d[k][n]
//   base[n]  = b1[n] + sum_k c[k]*(W1a[k][n] + W1c[k][n])
// ---------------------------------------------------------------------------
__global__ __launch_bounds__(256) void k_wb(const float* __restrict__ cand,
                                            const float* __restrict__ W1,
                                            const float* __restrict__ b1,
                                            unsigned short* __restrict__ WbG,
                                            float* __restrict__ baseG) {
    int b = blockIdx.x, t = threadIdx.x;
    __shared__ float shC[DD];
    if (t < DD) shC[t] = cand[b * DD + t];
    __syncthreads();
    unsigned short* wb = WbG + (size_t)b * (NP * DD);
#pragma unroll
    for (int u = 0; u < 12; ++u) {              // 48*64/256
        int e = t + u * 256;
        int n = e >> 6, k = e & 63;
        float val = 0.f;
        if (n < HH)
            val = W1[(DD + k) * HH + n] - W1[(2 * DD + k) * HH + n] +
                  shC[k] * W1[(3 * DD + k) * HH + n];
        wb[e] = f2bf(val);
    }
    if (t < NP) {
        float v = 0.f;
        if (t < HH) {
            v = b1[t];
            for (int k = 0; k < DD; ++k)
                v += shC[k] * (W1[k * HH + t] + W1[(2 * DD + k) * HH + t]);
        }
        baseG[b * NP + t] = v;
    }
}

// ---------------------------------------------------------------------------
// Prologue: stage half of hist (fp32 -> bf16 LDS, packed cvt) + WbT/base.
// WB=true: vector-load precomputed WbG/baseG (1 barrier total).
// WB=false: rebuild from W1 in-block (fallback, 3 barriers).
// half0: local rows 0-111 (tiles 0-6); half1: rows 112-199 + 8 zero pads.
// ---------------------------------------------------------------------------
template <bool WB>
__device__ __forceinline__ void prologue(int b, int half, int t,
                                         const float* __restrict__ hist,
                                         const float* __restrict__ cand,
                                         const float* __restrict__ W1,
                                         const float* __restrict__ b1,
                                         const unsigned short* __restrict__ WbG,
                                         const float* __restrict__ baseG,
                                         unsigned short* shH, unsigned short* shWbT,
                                         float* shC, float* shBase,
                                         float (*shBaseP)[NP]) {
    const float4* src =
        (const float4*)(hist + ((size_t)b * SS + (half ? 112 : 0)) * DD);
    float4 v[7];
    uint4 w0 = {}, w1 = {};
    float bse = 0.f;
    if (WB) {
        const uint4* wsrc = (const uint4*)(WbG + (size_t)b * (NP * DD));
        w0 = wsrc[t];                       // 384 uint4 = 48x64 bf16
        if (t < 128) w1 = wsrc[256 + t];
        if (t < NP) bse = baseG[b * NP + t];
    } else {
        if (t < DD) shC[t] = cand[b * DD + t];
    }
    if (!half) {
#pragma unroll
        for (int u = 0; u < 7; ++u) v[u] = src[t + u * 256];   // 112*16 = 7*256
    } else {
#pragma unroll
        for (int u = 0; u < 5; ++u) v[u] = src[t + u * 256];   // 88*16 = 5.5*256
        if (t < 128) v[5] = src[t + 1280];
        *(unsigned*)&shH[(88 + (t >> 5)) * LDH + (t & 31) * 2] = 0;  // pad rows
    }
    if (!WB) __syncthreads();               // shC visible for fallback build
    // drain hist loads -> bf16 LDS (packed cvt, b64 writes)
#pragma unroll
    for (int u = 0; u < 7; ++u) {
        int i = t + u * 256;
        bool act = half ? (u < 5 || (u == 5 && t < 128)) : true;
        if (u < 6 || !half) {
            if (act) {
                int s = i >> 4, c = i & 15;
                uint2 o = {f2bf2(v[u].x, v[u].y), f2bf2(v[u].z, v[u].w)};
                *(uint2*)&shH[s * LDH + c * 4] = o;
            }
        }
    }
    if (WB) {
        *(uint4*)&shWbT[(t >> 3) * LDH + (t & 7) * 8] = w0;
        if (t < 128) *(uint4*)&shWbT[(32 + (t >> 3)) * LDH + (t & 7) * 8] = w1;
        if (t < NP) shBase[t] = bse;
        __syncthreads();                    // single barrier
    } else {
        for (int e = t; e < NP * DD; e += 256) {
            int n = e >> 6, k = e & 63;
            float val = 0.f;
            if (n < HH)
                val = W1[(DD + k) * HH + n] - W1[(2 * DD + k) * HH + n] +
                      shC[k] * W1[(3 * DD + k) * HH + n];
            shWbT[n * LDH + k] = f2bf(val);
        }
        if (t < 4 * NP) {
            int g = t / NP, j = t - g * NP;
            float p = 0.f;
            if (j < HH) {
#pragma unroll 4
                for (int k = 16 * g; k < 16 * g + 16; ++k)
                    p += shC[k] * (W1[k * HH + j] + W1[(2 * DD + k) * HH + j]);
            }
            shBaseP[g][j] = p;
        }
        __syncthreads();
        if (t < NP) {
            float val = (t < HH) ? b1[t] : 0.f;
            shBase[t] = val + shBaseP[0][t] + shBaseP[1][t] + shBaseP[2][t] +
                        shBaseP[3][t];
        }
        __syncthreads();
    }
}

__device__ __forceinline__ void load_bfrags(const unsigned short* shWbT, int lane,
                                            bf16x8 (&bfr)[3][2]) {
    int col = lane & 15, q = lane >> 4;
#pragma unroll
    for (int nt = 0; nt < 3; ++nt)
#pragma unroll
        for (int kt = 0; kt < 2; ++kt)
            bfr[nt][kt] = *(const bf16x8*)&shWbT[(nt * 16 + col) * LDH + kt * 32 + q * 8];
}

__device__ __forceinline__ void gemm_tile(const unsigned short* shH,
                                          const bf16x8 (&bfr)[3][2], int mt, int lane,
                                          f32x4 (&d)[3]) {
    int m = mt * 16 + (lane & 15), q = lane >> 4;
    d[0] = f32x4{0.f, 0.f, 0.f, 0.f};
    d[1] = f32x4{0.f, 0.f, 0.f, 0.f};
    d[2] = f32x4{0.f, 0.f, 0.f, 0.f};
#pragma unroll
    for (int kt = 0; kt < 2; ++kt) {
        bf16x8 a = *(const bf16x8*)&shH[m * LDH + kt * 32 + q * 8];
#pragma unroll
        for (int nt = 0; nt < 3; ++nt)
            d[nt] = __builtin_amdgcn_mfma_f32_16x16x32_bf16(a, bfr[nt][kt], d[nt], 0, 0, 0);
    }
}

// ---------------------------------------------------------------------------
// Pass 1: column sums of h and h^2 (BN batch statistics)
// ---------------------------------------------------------------------------
template <bool WB, bool RED>
__global__ __launch_bounds__(256, 6) void k_pass1(const float* __restrict__ hist,
                                                  const float* __restrict__ cand,
                                                  const float* __restrict__ W1,
                                                  const float* __restrict__ b1,
                                                  const unsigned short* __restrict__ WbG,
                                                  const float* __restrict__ baseG,
                                                  float* __restrict__ pstat,
                                                  float* __restrict__ gsum,
                                                  float* __restrict__ gsum2) {
    __shared__ unsigned short shH[112 * LDH];
    __shared__ unsigned short shWbT[NP * LDH];
    __shared__ float shC[WB ? 1 : DD], shBase[NP];
    __shared__ float shBaseP[WB ? 1 : 4][NP];
    __shared__ float shP1[4][NP], shP2[4][NP];
    int bx = blockIdx.x, b = bx >> 1, half = bx & 1;
    int t = threadIdx.x, wave = t >> 6, lane = t & 63;
    int col = lane & 15, q = lane >> 4;

    prologue<WB>(b, half, t, hist, cand, W1, b1, WbG, baseG, shH, shWbT, shC,
                 shBase, shBaseP);

    bf16x8 bfr[3][2];
    load_bfrags(shWbT, lane, bfr);
    float basev[3];
#pragma unroll
    for (int nt = 0; nt < 3; ++nt) basev[nt] = shBase[nt * 16 + col];

    const int NTl = half ? 6 : 7;
    float cs1[3] = {0.f, 0.f, 0.f}, cs2[3] = {0.f, 0.f, 0.f};
    for (int mt = wave; mt < NTl; mt += 4) {
        f32x4 d[3];
        gemm_tile(shH, bfr, mt, lane, d);
        if (half && mt == 5) {               // only ragged tile needs guards
            int grow0 = 192 + q * 4;
#pragma unroll
            for (int nt = 0; nt < 3; ++nt)
#pragma unroll
                for (int r = 0; r < 4; ++r)
                    if (grow0 + r < SS) {
                        float vv = d[nt][r] + basev[nt];
                        cs1[nt] += vv;
                        cs2[nt] += vv * vv;
                    }
        } else {
#pragma unroll
            for (int nt = 0; nt < 3; ++nt)
#pragma unroll
                for (int r = 0; r < 4; ++r) {
                    float vv = d[nt][r] + basev[nt];
                    cs1[nt] += vv;
                    cs2[nt] += vv * vv;
                }
        }
    }
#pragma unroll
    for (int nt = 0; nt < 3; ++nt) {
        cs1[nt] += __shfl_xor(cs1[nt], 16);
        cs1[nt] += __shfl_xor(cs1[nt], 32);
        cs2[nt] += __shfl_xor(cs2[nt], 16);
        cs2[nt] += __shfl_xor(cs2[nt], 32);
    }
    if (lane < 16) {
#pragma unroll
        for (int nt = 0; nt < 3; ++nt) {
            shP1[wave][nt * 16 + lane] = cs1[nt];
            shP2[wave][nt * 16 + lane] = cs2[nt];
        }
    }
    __syncthreads();
    if (RED) {
        if (t < HH)
            pstat[(size_t)bx * PSTRIDE + t] =
                shP1[0][t] + shP1[1][t] + shP1[2][t] + shP1[3][t];
        else if (t < 2 * HH) {
            int f = t - HH;
            pstat[(size_t)bx * PSTRIDE + t] =
                shP2[0][f] + shP2[1][f] + shP2[2][f] + shP2[3][f];
        }
    } else {
        if (t < HH) {
            atomicAdd(gsum + t, shP1[0][t] + shP1[1][t] + shP1[2][t] + shP1[3][t]);
            atomicAdd(gsum2 + t, shP2[0][t] + shP2[1][t] + shP2[2][t] + shP2[3][t]);
        }
    }
}

// ---------------------------------------------------------------------------
// Stats reduce (RED): block f reduces feature-f partials over 8192 blocks.
// ---------------------------------------------------------------------------
__global__ __launch_bounds__(256) void k_stats_red(const float* __restrict__ pstat,
                                                   const float* __restrict__ gamma,
                                                   const float* __restrict__ beta,
                                                   float* __restrict__ A,
                                                   float* __restrict__ Bc) {
    int f = blockIdx.x, t = threadIdx.x;
    if (f >= HH) {
        if (t == 0) { A[f] = 0.f; Bc[f] = 0.f; }
        return;
    }
    float s1 = 0.f, s2 = 0.f;
    for (int r = t; r < NPB; r += 256) {
        s1 += pstat[(size_t)r * PSTRIDE + f];
        s2 += pstat[(size_t)r * PSTRIDE + HH + f];
    }
#pragma unroll
    for (int off = 1; off < 64; off <<= 1) {
        s1 += __shfl_xor(s1, off);
        s2 += __shfl_xor(s2, off);
    }
    __shared__ float a1[4], a2[4];
    if ((t & 63) == 0) { a1[t >> 6] = s1; a2[t >> 6] = s2; }
    __syncthreads();
    if (t == 0) {
        s1 = a1[0] + a1[1] + a1[2] + a1[3];
        s2 = a2[0] + a2[1] + a2[2] + a2[3];
        float mu = s1 * (1.0f / NROWSF);
        float var = s2 * (1.0f / NROWSF) - mu * mu;
        float a = rsqrtf(var + 1e-5f) * gamma[f];
        A[f] = a;
        Bc[f] = beta[f] - mu * a;
    }
}

// Atomic-fallback stats
__global__ void k_stats(const float* __restrict__ gsum, const float* __restrict__ gsum2,
                        const float* __restrict__ gamma, const float* __restrict__ beta,
                        float* __restrict__ A, float* __restrict__ Bc) {
    int t = threadIdx.x;
    if (t < NP) {
        if (t < HH) {
            float mu = gsum[t] * (1.0f / NROWSF);
            float var = gsum2[t] * (1.0f / NROWSF) - mu * mu;
            float a = rsqrtf(var + 1e-5f) * gamma[t];
            A[t] = a;
            Bc[t] = beta[t] - mu * a;
        } else {
            A[t] = 0.f;
            Bc[t] = 0.f;
        }
    }
}

// ---------------------------------------------------------------------------
// Pass 2: h -> BN affine -> Dice -> output linear -> pooling (from LDS bf16)
// ---------------------------------------------------------------------------
template <bool WB>
__global__ __launch_bounds__(256, 6) void k_pass2(const float* __restrict__ hist,
                                                  const float* __restrict__ cand,
                                                  const float* __restrict__ W1,
                                                  const float* __restrict__ b1,
                                                  const unsigned short* __restrict__ WbG,
                                                  const float* __restrict__ baseG,
                                                  const float* __restrict__ Acoef,
                                                  const float* __restrict__ Bcoef,
                                                  const float* __restrict__ alpha,
                                                  const float* __restrict__ W2,
                                                  const float* __restrict__ b2,
                                                  float* __restrict__ out) {
    __shared__ unsigned short shH[112 * LDH];
    __shared__ unsigned short shWbT[NP * LDH];
    __shared__ float shC[WB ? 1 : DD], shBase[NP];
    __shared__ float shBaseP[WB ? 1 : 4][NP];
    __shared__ float shW[112];
    __shared__ float shPool[4][DD];
    int bx = blockIdx.x, b = bx >> 1, half = bx & 1;
    int t = threadIdx.x, wave = t >> 6, lane = t & 63;
    int col = lane & 15, q = lane >> 4;

    prologue<WB>(b, half, t, hist, cand, W1, b1, WbG, baseG, shH, shWbT, shC,
                 shBase, shBaseP);

    bf16x8 bfr[3][2];
    load_bfrags(shWbT, lane, bfr);
    float baseAB[3], Ar[3], W2r[3];
#pragma unroll
    for (int nt = 0; nt < 3; ++nt) {
        int c = nt * 16 + col;
        Ar[nt] = Acoef[c];
        baseAB[nt] = fmaf(shBase[c], Ar[nt], Bcoef[c]);  // fold base into affine
        W2r[nt] = (c < HH) ? W2[c] : 0.f;
    }
    float alv = alpha[0], one_m_alv = 1.0f - alv, b2v = b2[0];

    const int NTl = half ? 6 : 7;
    for (int mt = wave; mt < NTl; mt += 4) {
        f32x4 d[3];
        gemm_tile(shH, bfr, mt, lane, d);
        float hp[3][4];
#pragma unroll
        for (int nt = 0; nt < 3; ++nt)
#pragma unroll
            for (int r = 0; r < 4; ++r)
                hp[nt][r] = fmaf(d[nt][r], Ar[nt], baseAB[nt]);
        float s1[4], s2[4], wsum[4];
#pragma unroll
        for (int r = 0; r < 4; ++r) {
            s1[r] = hp[0][r] + hp[1][r] + hp[2][r];
            s2[r] = hp[0][r] * hp[0][r] + hp[1][r] * hp[1][r] + hp[2][r] * hp[2][r];
            s1[r] += __shfl_xor(s1[r], 1);
            s1[r] += __shfl_xor(s1[r], 2);
            s1[r] += __shfl_xor(s1[r], 4);
            s1[r] += __shfl_xor(s1[r], 8);
            s2[r] += __shfl_xor(s2[r], 1);
            s2[r] += __shfl_xor(s2[r], 2);
            s2[r] += __shfl_xor(s2[r], 4);
            s2[r] += __shfl_xor(s2[r], 8);
        }
#pragma unroll
        for (int r = 0; r < 4; ++r) {
            float avg = s1[r] * (1.0f / (float)HH);
            float var = s2[r] * (1.0f / (float)HH) - avg * avg;
            float inv = rsqrtf(var + 1e-3f);
            float wv = 0.f;
#pragma unroll
            for (int nt = 0; nt < 3; ++nt) {
                float z = (hp[nt][r] - avg) * inv;
                float ps = 1.0f / (1.0f + __expf(-z));
                float f = fmaf(ps, one_m_alv, alv);      // ps + (1-ps)*alpha
                wv = fmaf(hp[nt][r] * f, W2r[nt], wv);
            }
            wsum[r] = wv;
            wsum[r] += __shfl_xor(wsum[r], 1);
            wsum[r] += __shfl_xor(wsum[r], 2);
            wsum[r] += __shfl_xor(wsum[r], 4);
            wsum[r] += __shfl_xor(wsum[r], 8);
        }
        if (col == 0) {                      // pad-row w's land in shW[88..95], unread
            float4 o = {wsum[0] + b2v, wsum[1] + b2v, wsum[2] + b2v, wsum[3] + b2v};
            *(float4*)&shW[mt * 16 + q * 4] = o;
        }
    }
    __syncthreads();
    // pooling from the bf16 LDS tile: out[b][d] += sum_s w[s]*hist[s][d]
    {
        const int nR = half ? 88 : 112;
        float p = 0.f;
        for (int s = wave; s < nR; s += 4)
            p = fmaf(shW[s], bf2f(shH[s * LDH + lane]), p);
        shPool[wave][lane] = p;
    }
    __syncthreads();
    if (t < DD)
        atomicAdd(out + b * DD + t,
                  shPool[0][t] + shPool[1][t] + shPool[2][t] + shPool[3][t]);
}

// ---------------------------------------------------------------------------
extern "C" void kernel_launch(void* const* d_in, const int* in_sizes, int n_in,
                              void* d_out, int out_size, void* d_ws, size_t ws_size,
                              hipStream_t stream) {
    const float* hist = (const float*)d_in[0];
    const float* cand = (const float*)d_in[1];
    const float* W1 = (const float*)d_in[2];
    const float* b1 = (const float*)d_in[3];
    const float* gamma = (const float*)d_in[4];
    const float* beta = (const float*)d_in[5];
    const float* alpha = (const float*)d_in[6];
    const float* W2 = (const float*)d_in[7];
    const float* b2 = (const float*)d_in[8];
    float* out = (float*)d_out;
    float* ws = (float*)d_ws;

    const size_t pstatF = (size_t)NPB * PSTRIDE;     // 655360 floats
    const size_t baseF = (size_t)BB * NP;            // 196608 floats
    const size_t wbBytes = (size_t)BB * NP * DD * 2; // 25.17 MB
    const size_t fullNeed = (pstatF + 2 * NP + baseF) * 4 + wbBytes;  // ~28.6 MB
    const size_t midNeed = (pstatF + 2 * NP) * 4;                     // ~2.63 MB

    hipMemsetAsync(out, 0, (size_t)out_size * sizeof(float), stream);
    if (ws_size >= fullNeed) {
        float* pstat = ws;
        float* A = pstat + pstatF;
        float* Bc = A + NP;
        float* baseG = Bc + NP;
        unsigned short* WbG = (unsigned short*)(baseG + baseF);
        k_wb<<<BB, 256, 0, stream>>>(cand, W1, b1, WbG, baseG);
        k_pass1<true, true><<<NPB, 256, 0, stream>>>(hist, cand, W1, b1, WbG, baseG,
                                                     pstat, nullptr, nullptr);
        k_stats_red<<<NP, 256, 0, stream>>>(pstat, gamma, beta, A, Bc);
        k_pass2<true><<<NPB, 256, 0, stream>>>(hist, cand, W1, b1, WbG, baseG, A, Bc,
                                               alpha, W2, b2, out);
    } else if (ws_size >= midNeed) {
        float* pstat = ws;
        float* A = pstat + pstatF;
        float* Bc = A + NP;
        k_pass1<false, true><<<NPB, 256, 0, stream>>>(hist, cand, W1, b1, nullptr,
                                                      nullptr, pstat, nullptr, nullptr);
        k_stats_red<<<NP, 256, 0, stream>>>(pstat, gamma, beta, A, Bc);
        k_pass2<false><<<NPB, 256, 0, stream>>>(hist, cand, W1, b1, nullptr, nullptr,
                                                A, Bc, alpha, W2, b2, out);
    } else {
        float* gsum = ws;
        float* gsum2 = ws + NP;
        float* A = ws + 2 * NP;
        float* Bc = ws + 3 * NP;
        hipMemsetAsync(gsum, 0, 2 * NP * sizeof(float), stream);
        k_pass1<false, false><<<NPB, 256, 0, stream>>>(hist, cand, W1, b1, nullptr,
                                                       nullptr, nullptr, gsum, gsum2);
        k_stats<<<1, 64, 0, stream>>>(gsum, gsum2, gamma, beta, A, Bc);
        k_pass2<false><<<NPB, 256, 0, stream>>>(hist, cand, W1, b1, nullptr, nullptr,
                                                A, Bc, alpha, W2, b2, out);
    }
}